// Round 1
// baseline (2138.045 us; speedup 1.0000x reference)
//
#include <hip/hip_runtime.h>
#include <math.h>

static inline int cdiv(int a, int b){ return (a + b - 1) / b; }

// ---------------- graph construction ----------------

__global__ void k_count0(const int* __restrict__ dst, int* __restrict__ cnt, int E){
  int i = blockIdx.x*blockDim.x + threadIdx.x;
  if (i < E) atomicAdd(&cnt[dst[i]], 1);
}

__global__ void k_dinv(const int* __restrict__ cnt, float* __restrict__ dinv, int N){
  int i = blockIdx.x*blockDim.x + threadIdx.x;
  if (i < N) dinv[i] = rsqrtf((float)cnt[i] + 2.0f);
}

// single-block exclusive scan (in has nIn entries, out gets nOut = nIn+1 incl. total)
__global__ void k_exscan(const int* __restrict__ in, int* __restrict__ out, int nIn, int nOut){
  __shared__ int buf[1024];
  __shared__ int carry;
  int t = threadIdx.x;
  if (t == 0) carry = 0;
  __syncthreads();
  for (int base = 0; base < nOut; base += 1024){
    int i = base + t;
    int v = (i < nIn) ? in[i] : 0;
    buf[t] = v; __syncthreads();
    for (int o = 1; o < 1024; o <<= 1){
      int u = (t >= o) ? buf[t-o] : 0;
      __syncthreads();
      buf[t] += u;
      __syncthreads();
    }
    if (i < nOut) out[i] = carry + buf[t] - v;
    __syncthreads();
    if (t == 0) carry += buf[1023];
    __syncthreads();
  }
}

__global__ void k_fill0(const int* __restrict__ src, const int* __restrict__ dst,
                        const int* __restrict__ rowptr, int* __restrict__ fill,
                        int* __restrict__ cols, int E){
  int i = blockIdx.x*blockDim.x + threadIdx.x;
  if (i >= E) return;
  int d = dst[i];
  int pos = rowptr[d] + atomicAdd(&fill[d], 1);
  cols[pos] = src[i];
}

__global__ void k_count_mapped(const int* __restrict__ src, const int* __restrict__ dst,
                               const int* __restrict__ nidx, int* __restrict__ cnt, int E){
  int i = blockIdx.x*blockDim.x + threadIdx.x;
  if (i >= E) return;
  int s = nidx[src[i]], d = nidx[dst[i]];
  if (s >= 0 && d >= 0) atomicAdd(&cnt[d], 1);
}

__global__ void k_fill_mapped(const int* __restrict__ src, const int* __restrict__ dst,
                              const int* __restrict__ nidx, const int* __restrict__ rowptr,
                              int* __restrict__ fill, int* __restrict__ cols, int E){
  int i = blockIdx.x*blockDim.x + threadIdx.x;
  if (i >= E) return;
  int s = nidx[src[i]], d = nidx[dst[i]];
  if (s >= 0 && d >= 0){
    int pos = rowptr[d] + atomicAdd(&fill[d], 1);
    cols[pos] = s;
  }
}

// level-2 CSR built from level-1 CSR (no atomics: one thread per level-1 node)
__global__ void k_count_csr(const int* __restrict__ rowptr1, const int* __restrict__ cols1,
                            const int* __restrict__ nidx, int* __restrict__ cnt, int N1){
  int n = blockIdx.x*blockDim.x + threadIdx.x;
  if (n >= N1) return;
  int m = nidx[n];
  if (m < 0) return;
  int c = 0;
  int je = rowptr1[n+1];
  for (int j = rowptr1[n]; j < je; ++j) c += (nidx[cols1[j]] >= 0);
  cnt[m] = c;
}

__global__ void k_fill_csr(const int* __restrict__ rowptr1, const int* __restrict__ cols1,
                           const int* __restrict__ nidx, const int* __restrict__ rowptr2,
                           int* __restrict__ cols2, int N1){
  int n = blockIdx.x*blockDim.x + threadIdx.x;
  if (n >= N1) return;
  int m = nidx[n];
  if (m < 0) return;
  int pos = rowptr2[m];
  int je = rowptr1[n+1];
  for (int j = rowptr1[n]; j < je; ++j){
    int s = nidx[cols1[j]];
    if (s >= 0) cols2[pos++] = s;
  }
}

// ---------------- dense GEMM: Out[N,M] = A[N,K] @ W[K,M] (+bias)(+relu) ----------------

__global__ __launch_bounds__(256) void k_gemm(const float* __restrict__ A, const float* __restrict__ W,
                     const float* __restrict__ bias, float* __restrict__ Out,
                     int N, int K, int M, int act)
{
  __shared__ alignas(16) float As[16][68];
  __shared__ alignas(16) float Bs[16][68];
  int row0 = blockIdx.x*64, col0 = blockIdx.y*64;
  int tid = threadIdx.x;
  int tr = tid >> 4, tc = tid & 15;
  float acc[4][4] = {};
  for (int k0 = 0; k0 < K; k0 += 16){
#pragma unroll
    for (int i = 0; i < 4; ++i){
      int idx = tid + i*256;            // 0..1023
      int r  = idx >> 4, kk  = idx & 15;   // A tile 64x16
      int rr = row0 + r;
      As[kk][r] = (rr < N) ? A[(size_t)rr*K + k0 + kk] : 0.f;
      int kk2 = idx >> 6, c = idx & 63;    // B tile 16x64
      int cc = col0 + c;
      Bs[kk2][c] = (cc < M) ? W[(size_t)(k0 + kk2)*M + cc] : 0.f;
    }
    __syncthreads();
#pragma unroll
    for (int kk = 0; kk < 16; ++kk){
      float4 av = *(const float4*)&As[kk][tr*4];
      float4 bv = *(const float4*)&Bs[kk][tc*4];
      float a[4] = {av.x, av.y, av.z, av.w};
      float b[4] = {bv.x, bv.y, bv.z, bv.w};
#pragma unroll
      for (int i = 0; i < 4; ++i)
#pragma unroll
        for (int j = 0; j < 4; ++j) acc[i][j] = fmaf(a[i], b[j], acc[i][j]);
    }
    __syncthreads();
  }
#pragma unroll
  for (int i = 0; i < 4; ++i){
    int r = row0 + tr*4 + i;
    if (r >= N) continue;
#pragma unroll
    for (int j = 0; j < 4; ++j){
      int c = col0 + tc*4 + j;
      if (c >= M) continue;
      float v = acc[i][j];
      if (bias) v += bias[c];
      if (act) v = fmaxf(v, 0.f);
      Out[(size_t)r*M + c] = v;
    }
  }
}

// ---------------- batch norm (training mode, biased var) ----------------

__global__ void k_bn_stats(const float* __restrict__ X, float* __restrict__ acc, int N, int C){
  int col = threadIdx.x % C;
  int rg  = threadIdx.x / C;
  int R   = blockDim.x / C;
  float s = 0.f, s2 = 0.f;
  for (int r = blockIdx.x*R + rg; r < N; r += gridDim.x*R){
    float v = X[(size_t)r*C + col];
    s += v; s2 += v*v;
  }
  __shared__ float sh[256], sh2[256];
  sh[threadIdx.x] = s; sh2[threadIdx.x] = s2;
  __syncthreads();
  if (rg == 0){
    for (int r = 1; r < R; ++r){ s += sh[r*C + col]; s2 += sh2[r*C + col]; }
    atomicAdd(&acc[col], s);
    atomicAdd(&acc[C + col], s2);
  }
}

__global__ void k_bn_final(const float* __restrict__ acc, const float* __restrict__ g,
                           const float* __restrict__ b, float* __restrict__ ss, int N, int C){
  int c = threadIdx.x;
  if (c >= C) return;
  float mu  = acc[c] / (float)N;
  float var = acc[C + c] / (float)N - mu*mu;
  float sc  = rsqrtf(var + 1e-5f) * g[c];
  ss[c]     = sc;
  ss[C + c] = b[c] - mu*sc;
}

__global__ void k_bn_apply(const float* __restrict__ X, float* __restrict__ Y,
                           const float* __restrict__ ss, int total, int C, int relu){
  int i = blockIdx.x*blockDim.x + threadIdx.x;
  if (i >= total) return;
  int c = i % C;
  float v = X[i]*ss[c] + ss[C + c];
  if (relu) v = fmaxf(v, 0.f);
  Y[i] = v;
}

// ---------------- GCN aggregation: out = sum_in norm*h[src] + 2*dinv^2*h[self] + b ----------------

template<int C>
__global__ void k_agg(const float* __restrict__ h, const int* __restrict__ rowptr,
                      const int* __restrict__ cols, const float* __restrict__ dinv,
                      const float* __restrict__ bias, float* __restrict__ out,
                      int N, int relu)
{
  constexpr int TPN = (C < 64) ? C : 64;
  constexpr int R = C / TPN;
  int gid  = blockIdx.x*blockDim.x + threadIdx.x;
  int node = gid / TPN;
  int lane = gid % TPN;
  if (node >= N) return;
  float di = dinv[node];
  float acc[R];
#pragma unroll
  for (int r = 0; r < R; ++r) acc[r] = 0.f;
  int je = rowptr[node+1];
  for (int j = rowptr[node]; j < je; ++j){
    int s = cols[j];
    float wgt = dinv[s]*di;
#pragma unroll
    for (int r = 0; r < R; ++r) acc[r] += wgt * h[(size_t)s*C + lane + r*TPN];
  }
  float sw = 2.f*di*di;
#pragma unroll
  for (int r = 0; r < R; ++r){
    int c = lane + r*TPN;
    float v = acc[r] + sw*h[(size_t)node*C + c] + bias[c];
    if (relu) v = fmaxf(v, 0.f);
    out[(size_t)node*C + c] = v;
  }
}

// ---------------- top-k pooling ----------------

__global__ void k_pnorm(const float* __restrict__ p, float* __restrict__ out, int C){
  __shared__ float sh[256];
  float s = 0.f;
  for (int i = threadIdx.x; i < C; i += 256){ float v = p[i]; s += v*v; }
  sh[threadIdx.x] = s; __syncthreads();
  for (int o = 128; o > 0; o >>= 1){
    if (threadIdx.x < o) sh[threadIdx.x] += sh[threadIdx.x + o];
    __syncthreads();
  }
  if (threadIdx.x == 0) out[0] = rsqrtf(sh[0]);   // 1/||p||
}

__global__ void k_score(const float* __restrict__ X, const float* __restrict__ p,
                        const float* __restrict__ pn, float* __restrict__ val,
                        unsigned int* __restrict__ key, int N, int C){
  int wid  = (blockIdx.x*blockDim.x + threadIdx.x) >> 6;
  int lane = threadIdx.x & 63;
  if (wid >= N) return;
  float s = 0.f;
  for (int c = lane; c < C; c += 64) s += X[(size_t)wid*C + c] * p[c];
  for (int o = 32; o > 0; o >>= 1) s += __shfl_down(s, o, 64);
  if (lane == 0){
    float sc = tanhf(s * pn[0]);
    val[wid] = sc;
    unsigned int b = __float_as_uint(sc);
    key[wid] = (b & 0x80000000u) ? ~b : (b | 0x80000000u);
  }
}

__global__ void k_hist_hi(const unsigned int* __restrict__ key, int N, unsigned int* __restrict__ hist){
  int i = blockIdx.x*blockDim.x + threadIdx.x;
  if (i < N) atomicAdd(&hist[key[i] >> 16], 1u);
}

__global__ void k_hist_lo(const unsigned int* __restrict__ key, int N,
                          const int* __restrict__ state, unsigned int* __restrict__ hist){
  int i = blockIdx.x*blockDim.x + threadIdx.x;
  if (i >= N) return;
  unsigned int kk = key[i];
  if ((int)(kk >> 16) == state[1]) atomicAdd(&hist[kk & 0xffffu], 1u);
}

// find largest bin B with count(keys in bins > B) < k <= ... ; write bin and remaining
__global__ void k_scan_hist(const unsigned int* __restrict__ hist, int* __restrict__ state,
                            int karg, int kidx, int bidx, int ridx){
  __shared__ unsigned int part[1024];
  __shared__ unsigned int suff[1024];
  int t = threadIdx.x;
  unsigned int s = 0;
  int base = t*64;
  for (int j = 0; j < 64; ++j) s += hist[base + j];
  part[t] = s;
  suff[t] = s;
  __syncthreads();
  for (int o = 1; o < 1024; o <<= 1){
    unsigned int v = (t + o < 1024) ? suff[t + o] : 0u;
    __syncthreads();
    suff[t] += v;
    __syncthreads();
  }
  unsigned int k = (unsigned int)((kidx >= 0) ? state[kidx] : karg);
  unsigned int above = suff[t] - part[t];
  if (above < k && above + part[t] >= k){
    unsigned int cum = above;
    for (int b = 63; b >= 0; --b){
      unsigned int c = hist[base + b];
      if (cum + c >= k){ state[bidx] = base + b; state[ridx] = (int)(k - cum); break; }
      cum += c;
    }
  }
}

// ordered single-block pass: sel = (key>T) || (key==T && rank_among_equals < m)
__global__ void k_select(const unsigned int* __restrict__ key, int N,
                         const int* __restrict__ state, int* __restrict__ sel){
  __shared__ int buf[1024];
  __shared__ int carry;
  unsigned int T = ((unsigned int)state[1] << 16) | (unsigned int)state[3];
  int m = state[4];
  int t = threadIdx.x;
  if (t == 0) carry = 0;
  __syncthreads();
  for (int base = 0; base < N; base += 1024){
    int i = base + t;
    unsigned int kk = (i < N) ? key[i] : 0u;
    int eq = (i < N && kk == T) ? 1 : 0;
    buf[t] = eq; __syncthreads();
    for (int o = 1; o < 1024; o <<= 1){
      int u = (t >= o) ? buf[t-o] : 0;
      __syncthreads();
      buf[t] += u;
      __syncthreads();
    }
    int excl = buf[t] - eq;
    if (i < N) sel[i] = (kk > T) || (eq && (carry + excl) < m);
    __syncthreads();
    if (t == 0) carry += buf[1023];
    __syncthreads();
  }
}

__global__ void k_compact(const int* __restrict__ sel, int* __restrict__ nidx,
                          int* __restrict__ counter, int N){
  int i = blockIdx.x*blockDim.x + threadIdx.x;
  if (i >= N) return;
  if (sel[i]) nidx[i] = atomicAdd(counter, 1);
  else        nidx[i] = -1;
}

__global__ void k_pool(const float* __restrict__ X, const float* __restrict__ val,
                       const int* __restrict__ nidx, float* __restrict__ Y, int N, int C){
  int i = blockIdx.x*blockDim.x + threadIdx.x;
  int n = i / C, c = i % C;
  if (n >= N) return;
  int m = nidx[n];
  if (m >= 0) Y[(size_t)m*C + c] = X[i]*val[n];
}

__global__ void k_unpool(float* __restrict__ X, const float* __restrict__ D,
                         const int* __restrict__ nidx, int N, int C){
  int i = blockIdx.x*blockDim.x + threadIdx.x;
  int n = i / C, c = i % C;
  if (n >= N) return;
  int m = nidx[n];
  if (m >= 0) X[i] = (D[(size_t)m*C + c] + X[i])*0.5f;
}

// ---------------- launch ----------------

extern "C" void kernel_launch(void* const* d_in, const int* in_sizes, int n_in,
                              void* d_out, int out_size, void* d_ws, size_t ws_size,
                              hipStream_t stream)
{
  const float* x_in = (const float*)d_in[0];
  const int*   esrc = (const int*)d_in[1];
  const int*   edst = (const int*)d_in[2];
  const float* e0_mlp_W = (const float*)d_in[3];
  const float* e0_mlp_b = (const float*)d_in[4];
  const float* e0_bn1_g = (const float*)d_in[5];
  const float* e0_bn1_b = (const float*)d_in[6];
  const float* e0_conv_W= (const float*)d_in[7];
  const float* e0_conv_b= (const float*)d_in[8];
  const float* e0_n_g   = (const float*)d_in[9];
  const float* e0_n_b   = (const float*)d_in[10];
  const float* e1_p     = (const float*)d_in[11];
  const float* e1_mlp_W = (const float*)d_in[12];
  const float* e1_mlp_b = (const float*)d_in[13];
  const float* e1_bn1_g = (const float*)d_in[14];
  const float* e1_bn1_b = (const float*)d_in[15];
  const float* e1_conv_W= (const float*)d_in[16];
  const float* e1_conv_b= (const float*)d_in[17];
  const float* e1_n_g   = (const float*)d_in[18];
  const float* e1_n_b   = (const float*)d_in[19];
  const float* e2_p     = (const float*)d_in[20];
  const float* e2_mlp_W = (const float*)d_in[21];
  const float* e2_mlp_b = (const float*)d_in[22];
  const float* e2_bn1_g = (const float*)d_in[23];
  const float* e2_bn1_b = (const float*)d_in[24];
  const float* e2_conv_W= (const float*)d_in[25];
  const float* e2_conv_b= (const float*)d_in[26];
  const float* e2_n_g   = (const float*)d_in[27];
  const float* e2_n_b   = (const float*)d_in[28];
  const float* d2_W = (const float*)d_in[29];
  const float* d2_b = (const float*)d_in[30];
  const float* d1_W = (const float*)d_in[31];
  const float* d1_b = (const float*)d_in[32];
  const float* d0_W = (const float*)d_in[33];
  const float* d0_b = (const float*)d_in[34];
  float* out = (float*)d_out;

  const int N0 = in_sizes[0] / 16;
  const int E  = in_sizes[1];
  const int N1 = (N0 + 1) / 2;
  const int N2 = (N1 + 1) / 2;

  // ---- workspace carve ----
  char* w = (char*)d_ws;
  auto alloc = [&](size_t b)->void*{ void* p = (void*)w; w += (b + 255) & ~(size_t)255; return p; };
  float* x1 = (float*)alloc((size_t)N0*64*4);
  float* x2 = (float*)alloc((size_t)N1*128*4);
  float* x3 = (float*)alloc((size_t)N2*256*4);
  size_t tmax = (size_t)N0*64*4;
  float* tA = (float*)alloc(tmax);
  float* tB = (float*)alloc(tmax);
  int* rowptr0 = (int*)alloc((size_t)(N0+1)*4);
  int* rowptr1 = (int*)alloc((size_t)(N1+1)*4);
  int* rowptr2 = (int*)alloc((size_t)(N2+1)*4);
  int* cnt  = (int*)alloc((size_t)(N0+1)*4);
  int* fill = (int*)alloc((size_t)N0*4);
  int* cols0 = (int*)alloc((size_t)E*4);
  int* cols1 = (int*)alloc((size_t)E*4);
  int* cols2 = (int*)alloc((size_t)E*4);
  float* dinv0 = (float*)alloc((size_t)N0*4);
  float* dinv1 = (float*)alloc((size_t)N1*4);
  float* dinv2 = (float*)alloc((size_t)N2*4);
  int* nidx1 = (int*)alloc((size_t)N0*4);
  int* nidx2 = (int*)alloc((size_t)N1*4);
  float* val = (float*)alloc((size_t)N0*4);
  unsigned int* key = (unsigned int*)alloc((size_t)N0*4);
  int* sel = (int*)alloc((size_t)N0*4);
  unsigned int* hist = (unsigned int*)alloc((size_t)65536*4);
  int* state = (int*)alloc(64);
  float* bnacc = (float*)alloc(512*4);
  float* ss = (float*)alloc(512*4);
  float* pn = (float*)alloc(256);
  int* counter = (int*)alloc(256);
  if ((size_t)(w - (char*)d_ws) > ws_size) return;  // ws too small: bail cleanly

  auto run_gemm = [&](const float* A, const float* W, const float* bias, float* O,
                      int N, int K, int M, int act){
    k_gemm<<<dim3(cdiv(N,64), cdiv(M,64)), dim3(256), 0, stream>>>(A, W, bias, O, N, K, M, act);
  };
  auto run_bn = [&](const float* Xin, float* Yout, const float* g, const float* b,
                    int N, int C, int relu){
    hipMemsetAsync(bnacc, 0, 2*C*sizeof(float), stream);
    k_bn_stats<<<dim3(256), dim3(256), 0, stream>>>(Xin, bnacc, N, C);
    k_bn_final<<<dim3(1), dim3(C), 0, stream>>>(bnacc, g, b, ss, N, C);
    int total = N*C;
    k_bn_apply<<<dim3(cdiv(total,256)), dim3(256), 0, stream>>>(Xin, Yout, ss, total, C, relu);
  };
  auto run_agg = [&](const float* h, const int* rp, const int* cl, const float* dv,
                     const float* bias, float* o, int N, int C, int relu){
    int tpn = (C < 64) ? C : 64;
    dim3 g(cdiv(N*tpn, 256));
    switch (C){
      case 16:  k_agg<16> <<<g, dim3(256), 0, stream>>>(h, rp, cl, dv, bias, o, N, relu); break;
      case 64:  k_agg<64> <<<g, dim3(256), 0, stream>>>(h, rp, cl, dv, bias, o, N, relu); break;
      case 128: k_agg<128><<<g, dim3(256), 0, stream>>>(h, rp, cl, dv, bias, o, N, relu); break;
      case 256: k_agg<256><<<g, dim3(256), 0, stream>>>(h, rp, cl, dv, bias, o, N, relu); break;
    }
  };
  auto run_topk = [&](const float* X, const float* p, int N, int C, int k, int* nidx){
    k_pnorm<<<dim3(1), dim3(256), 0, stream>>>(p, pn, C);
    k_score<<<dim3(cdiv(N*64,256)), dim3(256), 0, stream>>>(X, p, pn, val, key, N, C);
    hipMemsetAsync(hist, 0, 65536*4, stream);
    k_hist_hi<<<dim3(cdiv(N,256)), dim3(256), 0, stream>>>(key, N, hist);
    k_scan_hist<<<dim3(1), dim3(1024), 0, stream>>>(hist, state, k, -1, 1, 2);
    hipMemsetAsync(hist, 0, 65536*4, stream);
    k_hist_lo<<<dim3(cdiv(N,256)), dim3(256), 0, stream>>>(key, N, state, hist);
    k_scan_hist<<<dim3(1), dim3(1024), 0, stream>>>(hist, state, 0, 2, 3, 4);
    k_select<<<dim3(1), dim3(1024), 0, stream>>>(key, N, state, sel);
    hipMemsetAsync(counter, 0, 4, stream);
    k_compact<<<dim3(cdiv(N,256)), dim3(256), 0, stream>>>(sel, nidx, counter, N);
  };

  // ---- CSR level 0 (full graph, reused by encoder0 and decoder0) ----
  hipMemsetAsync(cnt, 0, (size_t)(N0+1)*4, stream);
  k_count0<<<dim3(cdiv(E,256)), dim3(256), 0, stream>>>(edst, cnt, E);
  k_dinv<<<dim3(cdiv(N0,256)), dim3(256), 0, stream>>>(cnt, dinv0, N0);
  k_exscan<<<dim3(1), dim3(1024), 0, stream>>>(cnt, rowptr0, N0, N0+1);
  hipMemsetAsync(fill, 0, (size_t)N0*4, stream);
  k_fill0<<<dim3(cdiv(E,256)), dim3(256), 0, stream>>>(esrc, edst, rowptr0, fill, cols0, E);

  // ---- encoder0 ----
  run_gemm(x_in, e0_mlp_W, e0_mlp_b, tA, N0, 16, 64, 1);
  run_bn(tA, tA, e0_bn1_g, e0_bn1_b, N0, 64, 0);
  run_gemm(tA, e0_conv_W, nullptr, tB, N0, 64, 64, 0);
  run_agg(tB, rowptr0, cols0, dinv0, e0_conv_b, tA, N0, 64, 0);
  run_bn(tA, x1, e0_n_g, e0_n_b, N0, 64, 1);

  // ---- pool1 + CSR level 1 ----
  run_topk(x1, e1_p, N0, 64, N1, nidx1);
  k_pool<<<dim3(cdiv(N0*64,256)), dim3(256), 0, stream>>>(x1, val, nidx1, tA, N0, 64);
  hipMemsetAsync(cnt, 0, (size_t)(N1+1)*4, stream);
  k_count_mapped<<<dim3(cdiv(E,256)), dim3(256), 0, stream>>>(esrc, edst, nidx1, cnt, E);
  k_dinv<<<dim3(cdiv(N1,256)), dim3(256), 0, stream>>>(cnt, dinv1, N1);
  k_exscan<<<dim3(1), dim3(1024), 0, stream>>>(cnt, rowptr1, N1, N1+1);
  hipMemsetAsync(fill, 0, (size_t)N1*4, stream);
  k_fill_mapped<<<dim3(cdiv(E,256)), dim3(256), 0, stream>>>(esrc, edst, nidx1, rowptr1, fill, cols1, E);

  // ---- encoder1 ----
  run_gemm(tA, e1_mlp_W, e1_mlp_b, tB, N1, 64, 128, 1);
  run_bn(tB, tB, e1_bn1_g, e1_bn1_b, N1, 128, 0);
  run_gemm(tB, e1_conv_W, nullptr, tA, N1, 128, 128, 0);
  run_agg(tA, rowptr1, cols1, dinv1, e1_conv_b, tB, N1, 128, 0);
  run_bn(tB, x2, e1_n_g, e1_n_b, N1, 128, 1);

  // ---- pool2 + CSR level 2 (built from CSR1) ----
  run_topk(x2, e2_p, N1, 128, N2, nidx2);
  k_pool<<<dim3(cdiv(N1*128,256)), dim3(256), 0, stream>>>(x2, val, nidx2, tA, N1, 128);
  k_count_csr<<<dim3(cdiv(N1,256)), dim3(256), 0, stream>>>(rowptr1, cols1, nidx2, cnt, N1);
  k_dinv<<<dim3(cdiv(N2,256)), dim3(256), 0, stream>>>(cnt, dinv2, N2);
  k_exscan<<<dim3(1), dim3(1024), 0, stream>>>(cnt, rowptr2, N2, N2+1);
  k_fill_csr<<<dim3(cdiv(N1,256)), dim3(256), 0, stream>>>(rowptr1, cols1, nidx2, rowptr2, cols2, N1);

  // ---- encoder2 ----
  run_gemm(tA, e2_mlp_W, e2_mlp_b, tB, N2, 128, 256, 1);
  run_bn(tB, tB, e2_bn1_g, e2_bn1_b, N2, 256, 0);
  run_gemm(tB, e2_conv_W, nullptr, tA, N2, 256, 256, 0);
  run_agg(tA, rowptr2, cols2, dinv2, e2_conv_b, tB, N2, 256, 0);
  run_bn(tB, x3, e2_n_g, e2_n_b, N2, 256, 1);

  // ---- decoder2 + unpool into x2 ----
  run_gemm(x3, d2_W, nullptr, tA, N2, 256, 128, 0);
  run_agg(tA, rowptr2, cols2, dinv2, d2_b, tB, N2, 128, 1);
  k_unpool<<<dim3(cdiv(N1*128,256)), dim3(256), 0, stream>>>(x2, tB, nidx2, N1, 128);

  // ---- decoder1 + unpool into x1 ----
  run_gemm(x2, d1_W, nullptr, tA, N1, 128, 64, 0);
  run_agg(tA, rowptr1, cols1, dinv1, d1_b, tB, N1, 64, 1);
  k_unpool<<<dim3(cdiv(N0*64,256)), dim3(256), 0, stream>>>(x1, tB, nidx1, N0, 64);

  // ---- decoder0 -> output ----
  run_gemm(x1, d0_W, nullptr, tA, N0, 64, 16, 0);
  run_agg(tA, rowptr0, cols0, dinv0, d0_b, out, N0, 16, 0);
}

// Round 2
// 1542.783 us; speedup vs baseline: 1.3858x; 1.3858x over previous
//
#include <hip/hip_runtime.h>
#include <math.h>

static inline int cdiv(int a, int b){ return (a + b - 1) / b; }

#define SCAN_CHUNK 4096   // 256 threads x 16 items

// ---------------- graph construction ----------------

__global__ void k_count0(const int* __restrict__ dst, int* __restrict__ cnt, int E){
  int i = blockIdx.x*blockDim.x + threadIdx.x;
  if (i < E) atomicAdd(&cnt[dst[i]], 1);
}

__global__ void k_fill0(const int* __restrict__ src, const int* __restrict__ dst,
                        const int* __restrict__ rowptr, int* __restrict__ fill,
                        int* __restrict__ cols, int E){
  int i = blockIdx.x*blockDim.x + threadIdx.x;
  if (i >= E) return;
  int d = dst[i];
  int pos = rowptr[d] + atomicAdd(&fill[d], 1);
  cols[pos] = src[i];
}

__global__ void k_count_mapped(const int* __restrict__ src, const int* __restrict__ dst,
                               const int* __restrict__ nidx, int* __restrict__ cnt, int E){
  int i = blockIdx.x*blockDim.x + threadIdx.x;
  if (i >= E) return;
  int s = nidx[src[i]], d = nidx[dst[i]];
  if (s >= 0 && d >= 0) atomicAdd(&cnt[d], 1);
}

__global__ void k_fill_mapped(const int* __restrict__ src, const int* __restrict__ dst,
                              const int* __restrict__ nidx, const int* __restrict__ rowptr,
                              int* __restrict__ fill, int* __restrict__ cols, int E){
  int i = blockIdx.x*blockDim.x + threadIdx.x;
  if (i >= E) return;
  int s = nidx[src[i]], d = nidx[dst[i]];
  if (s >= 0 && d >= 0){
    int pos = rowptr[d] + atomicAdd(&fill[d], 1);
    cols[pos] = s;
  }
}

__global__ void k_count_csr(const int* __restrict__ rowptr1, const int* __restrict__ cols1,
                            const int* __restrict__ nidx, int* __restrict__ cnt, int N1){
  int n = blockIdx.x*blockDim.x + threadIdx.x;
  if (n >= N1) return;
  int m = nidx[n];
  if (m < 0) return;
  int c = 0;
  int je = rowptr1[n+1];
  for (int j = rowptr1[n]; j < je; ++j) c += (nidx[cols1[j]] >= 0);
  cnt[m] = c;
}

__global__ void k_fill_csr(const int* __restrict__ rowptr1, const int* __restrict__ cols1,
                           const int* __restrict__ nidx, const int* __restrict__ rowptr2,
                           int* __restrict__ cols2, int N1){
  int n = blockIdx.x*blockDim.x + threadIdx.x;
  if (n >= N1) return;
  int m = nidx[n];
  if (m < 0) return;
  int pos = rowptr2[m];
  int je = rowptr1[n+1];
  for (int j = rowptr1[n]; j < je; ++j){
    int s = nidx[cols1[j]];
    if (s >= 0) cols2[pos++] = s;
  }
}

// ---------------- hierarchical exclusive scan (rowptr + fused dinv) ----------------

// pass1: per-block sums over SCAN_CHUNK elements (i < nIn)
__global__ __launch_bounds__(256) void k_scan_p1(const int* __restrict__ in, int nIn, int* __restrict__ bsum){
  __shared__ int sh[256];
  int base = blockIdx.x*SCAN_CHUNK;
  int end = min(base + SCAN_CHUNK, nIn);
  int s = 0;
  for (int i = base + threadIdx.x; i < end; i += 256) s += in[i];
  sh[threadIdx.x] = s; __syncthreads();
  for (int o = 128; o > 0; o >>= 1){
    if (threadIdx.x < o) sh[threadIdx.x] += sh[threadIdx.x + o];
    __syncthreads();
  }
  if (threadIdx.x == 0) bsum[blockIdx.x] = sh[0];
}

// pass2: single-block exclusive scan of nb (<=256) block sums
__global__ __launch_bounds__(256) void k_scan_p2(int* __restrict__ bsum, int nb){
  __shared__ int sh[256];
  int t = threadIdx.x;
  int v = (t < nb) ? bsum[t] : 0;
  sh[t] = v; __syncthreads();
  for (int o = 1; o < 256; o <<= 1){
    int u = (t >= o) ? sh[t-o] : 0;
    __syncthreads();
    sh[t] += u;
    __syncthreads();
  }
  if (t < nb) bsum[t] = sh[t] - v;
}

// pass3: local scan, write rowptr[0..nIn] and dinv
__global__ __launch_bounds__(256) void k_scan_p3(const int* __restrict__ cnt, const int* __restrict__ bsum,
                        int* __restrict__ rowptr, float* __restrict__ dinv, int nIn){
  int t = threadIdx.x;
  int tb = blockIdx.x*SCAN_CHUNK + t*16;
  int my[16]; int s = 0;
#pragma unroll
  for (int j = 0; j < 16; ++j){
    int i = tb + j;
    int v = (i < nIn) ? cnt[i] : 0;
    my[j] = v; s += v;
  }
  __shared__ int sh[256];
  sh[t] = s; __syncthreads();
  for (int o = 1; o < 256; o <<= 1){
    int u = (t >= o) ? sh[t-o] : 0;
    __syncthreads();
    sh[t] += u;
    __syncthreads();
  }
  int run = bsum[blockIdx.x] + sh[t] - s;
#pragma unroll
  for (int j = 0; j < 16; ++j){
    int i = tb + j;
    if (i < nIn){
      rowptr[i] = run;
      if (dinv) dinv[i] = rsqrtf((float)my[j] + 2.0f);
      run += my[j];
    } else if (i == nIn){
      rowptr[nIn] = run;
    }
  }
}

// ---------------- dense GEMM: Out[N,M] = A'[N,K] @ W[K,M] (+bias)(+relu)(+col stats) ----------------
// A' = ssA ? A*ssA[k] + ssA[K+k] : A   (folds a preceding BatchNorm-apply into the A load)
// stats: per-column atomic {sum, sumsq} of the written output (for a following BatchNorm)

__global__ __launch_bounds__(256) void k_gemm(const float* __restrict__ A, const float* __restrict__ W,
                     const float* __restrict__ bias, float* __restrict__ Out,
                     const float* __restrict__ ssA, float* __restrict__ stats,
                     int N, int K, int M, int act)
{
  __shared__ alignas(16) float As[16][68];
  __shared__ alignas(16) float Bs[16][68];
  int row0 = blockIdx.x*64, col0 = blockIdx.y*64;
  int tid = threadIdx.x;
  int tr = tid >> 4, tc = tid & 15;
  float acc[4][4] = {};
  for (int k0 = 0; k0 < K; k0 += 16){
#pragma unroll
    for (int i = 0; i < 4; ++i){
      int idx = tid + i*256;               // 0..1023
      int r  = idx >> 4, kk = idx & 15;    // A tile 64x16
      int rr = row0 + r;
      float av = 0.f;
      if (rr < N){
        av = A[(size_t)rr*K + k0 + kk];
        if (ssA) av = fmaf(av, ssA[k0 + kk], ssA[K + k0 + kk]);
      }
      As[kk][r] = av;
      int kk2 = idx >> 6, c = idx & 63;    // B tile 16x64
      int cc = col0 + c;
      Bs[kk2][c] = (cc < M) ? W[(size_t)(k0 + kk2)*M + cc] : 0.f;
    }
    __syncthreads();
#pragma unroll
    for (int kk = 0; kk < 16; ++kk){
      float4 av = *(const float4*)&As[kk][tr*4];
      float4 bv = *(const float4*)&Bs[kk][tc*4];
      float a[4] = {av.x, av.y, av.z, av.w};
      float b[4] = {bv.x, bv.y, bv.z, bv.w};
#pragma unroll
      for (int i = 0; i < 4; ++i)
#pragma unroll
        for (int j = 0; j < 4; ++j) acc[i][j] = fmaf(a[i], b[j], acc[i][j]);
    }
    __syncthreads();
  }
  float vv[4][4];
  bool rok[4];
#pragma unroll
  for (int i = 0; i < 4; ++i) rok[i] = (row0 + tr*4 + i) < N;
#pragma unroll
  for (int j = 0; j < 4; ++j){
    int c = col0 + tc*4 + j;
    bool cok = c < M;
#pragma unroll
    for (int i = 0; i < 4; ++i){
      float v = 0.f;
      if (cok){
        v = acc[i][j];
        if (bias) v += bias[c];
        if (act) v = fmaxf(v, 0.f);
        if (rok[i]) Out[(size_t)(row0 + tr*4 + i)*M + c] = v;
      }
      vv[i][j] = (rok[i] && cok) ? v : 0.f;
    }
  }
  if (stats){
    // per-column {sum, sumsq} for this block's 64x64 tile
#pragma unroll
    for (int j = 0; j < 4; ++j){
      float s = 0.f, s2 = 0.f;
#pragma unroll
      for (int i = 0; i < 4; ++i){ s += vv[i][j]; s2 = fmaf(vv[i][j], vv[i][j], s2); }
      As[tr][tc*4 + j] = s;
      Bs[tr][tc*4 + j] = s2;
    }
    __syncthreads();
    if (tid < 64){
      float s = 0.f, s2 = 0.f;
      for (int r = 0; r < 16; ++r){ s += As[r][tid]; s2 += Bs[r][tid]; }
      int cc = col0 + tid;
      if (cc < M){
        atomicAdd(&stats[cc], s);
        atomicAdd(&stats[M + cc], s2);
      }
    }
  }
}

// ---------------- batch norm ----------------

__global__ void k_bn_stats(const float* __restrict__ X, float* __restrict__ acc, int N, int C){
  int col = threadIdx.x % C;
  int rg  = threadIdx.x / C;
  int R   = blockDim.x / C;
  float s = 0.f, s2 = 0.f;
  for (int r = blockIdx.x*R + rg; r < N; r += gridDim.x*R){
    float v = X[(size_t)r*C + col];
    s += v; s2 += v*v;
  }
  __shared__ float sh[256], sh2[256];
  sh[threadIdx.x] = s; sh2[threadIdx.x] = s2;
  __syncthreads();
  if (rg == 0){
    for (int r = 1; r < R; ++r){ s += sh[r*C + col]; s2 += sh2[r*C + col]; }
    atomicAdd(&acc[col], s);
    atomicAdd(&acc[C + col], s2);
  }
}

__global__ void k_bn_final(const float* __restrict__ acc, const float* __restrict__ g,
                           const float* __restrict__ b, float* __restrict__ ss, int N, int C){
  int c = threadIdx.x;
  if (c >= C) return;
  float mu  = acc[c] / (float)N;
  float var = acc[C + c] / (float)N - mu*mu;
  float sc  = rsqrtf(var + 1e-5f) * g[c];
  ss[c]     = sc;
  ss[C + c] = b[c] - mu*sc;
}

__global__ void k_bn_apply(const float* __restrict__ X, float* __restrict__ Y,
                           const float* __restrict__ ss, int total, int C, int relu){
  int i = blockIdx.x*blockDim.x + threadIdx.x;
  if (i >= total) return;
  int c = i % C;
  float v = X[i]*ss[c] + ss[C + c];
  if (relu) v = fmaxf(v, 0.f);
  Y[i] = v;
}

// ---------------- GCN aggregation ----------------

template<int C>
__global__ void k_agg(const float* __restrict__ h, const int* __restrict__ rowptr,
                      const int* __restrict__ cols, const float* __restrict__ dinv,
                      const float* __restrict__ bias, float* __restrict__ out,
                      int N, int relu)
{
  constexpr int TPN = (C < 64) ? C : 64;
  constexpr int R = C / TPN;
  int gid  = blockIdx.x*blockDim.x + threadIdx.x;
  int node = gid / TPN;
  int lane = gid % TPN;
  if (node >= N) return;
  float di = dinv[node];
  float acc[R];
#pragma unroll
  for (int r = 0; r < R; ++r) acc[r] = 0.f;
  int je = rowptr[node+1];
  for (int j = rowptr[node]; j < je; ++j){
    int s = cols[j];
    float wgt = dinv[s]*di;
#pragma unroll
    for (int r = 0; r < R; ++r) acc[r] = fmaf(wgt, h[(size_t)s*C + lane + r*TPN], acc[r]);
  }
  float sw = 2.f*di*di;
#pragma unroll
  for (int r = 0; r < R; ++r){
    int c = lane + r*TPN;
    float v = acc[r] + sw*h[(size_t)node*C + c] + bias[c];
    if (relu) v = fmaxf(v, 0.f);
    out[(size_t)node*C + c] = v;
  }
}

// ---------------- top-k pooling ----------------

__global__ void k_pnorm(const float* __restrict__ p, float* __restrict__ out, int C){
  __shared__ float sh[256];
  float s = 0.f;
  for (int i = threadIdx.x; i < C; i += 256){ float v = p[i]; s += v*v; }
  sh[threadIdx.x] = s; __syncthreads();
  for (int o = 128; o > 0; o >>= 1){
    if (threadIdx.x < o) sh[threadIdx.x] += sh[threadIdx.x + o];
    __syncthreads();
  }
  if (threadIdx.x == 0) out[0] = rsqrtf(sh[0]);   // 1/||p||
}

__global__ void k_score(const float* __restrict__ X, const float* __restrict__ p,
                        const float* __restrict__ pn, float* __restrict__ val,
                        unsigned int* __restrict__ key, int N, int C){
  int wid  = (blockIdx.x*blockDim.x + threadIdx.x) >> 6;
  int lane = threadIdx.x & 63;
  if (wid >= N) return;
  float s = 0.f;
  for (int c = lane; c < C; c += 64) s += X[(size_t)wid*C + c] * p[c];
  for (int o = 32; o > 0; o >>= 1) s += __shfl_down(s, o, 64);
  if (lane == 0){
    float sc = tanhf(s * pn[0]);
    val[wid] = sc;
    unsigned int b = __float_as_uint(sc);
    key[wid] = (b & 0x80000000u) ? ~b : (b | 0x80000000u);
  }
}

__global__ void k_hist_hi(const unsigned int* __restrict__ key, int N, unsigned int* __restrict__ hist){
  int i = blockIdx.x*blockDim.x + threadIdx.x;
  if (i < N) atomicAdd(&hist[key[i] >> 16], 1u);
}

__global__ void k_hist_lo(const unsigned int* __restrict__ key, int N,
                          const int* __restrict__ state, unsigned int* __restrict__ hist){
  int i = blockIdx.x*blockDim.x + threadIdx.x;
  if (i >= N) return;
  unsigned int kk = key[i];
  if ((int)(kk >> 16) == state[1]) atomicAdd(&hist[kk & 0xffffu], 1u);
}

__global__ void k_scan_hist(const unsigned int* __restrict__ hist, int* __restrict__ state,
                            int karg, int kidx, int bidx, int ridx){
  __shared__ unsigned int part[1024];
  __shared__ unsigned int suff[1024];
  int t = threadIdx.x;
  unsigned int s = 0;
  int base = t*64;
  for (int j = 0; j < 64; ++j) s += hist[base + j];
  part[t] = s;
  suff[t] = s;
  __syncthreads();
  for (int o = 1; o < 1024; o <<= 1){
    unsigned int v = (t + o < 1024) ? suff[t + o] : 0u;
    __syncthreads();
    suff[t] += v;
    __syncthreads();
  }
  unsigned int k = (unsigned int)((kidx >= 0) ? state[kidx] : karg);
  unsigned int above = suff[t] - part[t];
  if (above < k && above + part[t] >= k){
    unsigned int cum = above;
    for (int b = 63; b >= 0; --b){
      unsigned int c = hist[base + b];
      if (cum + c >= k){ state[bidx] = base + b; state[ridx] = (int)(k - cum); break; }
      cum += c;
    }
  }
}

// ---------------- parallel selection + ordered compaction ----------------
// sel = (key>T) || (key==T && eq_rank<m); nidx = gt_before + min(eq_before, m)

__global__ __launch_bounds__(256) void k_sel_p1(const unsigned int* __restrict__ key, int n,
                       const int* __restrict__ state, int2* __restrict__ bcnt){
  unsigned int T = ((unsigned int)state[1] << 16) | (unsigned int)state[3];
  int base = blockIdx.x*SCAN_CHUNK;
  int end = min(base + SCAN_CHUNK, n);
  int gt = 0, eq = 0;
  for (int i = base + threadIdx.x; i < end; i += 256){
    unsigned int v = key[i];
    gt += (v > T); eq += (v == T);
  }
  __shared__ int sg[256], se[256];
  sg[threadIdx.x] = gt; se[threadIdx.x] = eq;
  __syncthreads();
  for (int o = 128; o > 0; o >>= 1){
    if (threadIdx.x < o){ sg[threadIdx.x] += sg[threadIdx.x + o]; se[threadIdx.x] += se[threadIdx.x + o]; }
    __syncthreads();
  }
  if (threadIdx.x == 0) bcnt[blockIdx.x] = make_int2(sg[0], se[0]);
}

__global__ __launch_bounds__(256) void k_sel_p2(int2* __restrict__ bcnt, int nb){
  __shared__ int sg[256], se[256];
  int t = threadIdx.x;
  int2 v = (t < nb) ? bcnt[t] : make_int2(0, 0);
  sg[t] = v.x; se[t] = v.y; __syncthreads();
  for (int o = 1; o < 256; o <<= 1){
    int a = (t >= o) ? sg[t-o] : 0;
    int b = (t >= o) ? se[t-o] : 0;
    __syncthreads();
    sg[t] += a; se[t] += b;
    __syncthreads();
  }
  if (t < nb) bcnt[t] = make_int2(sg[t] - v.x, se[t] - v.y);
}

__global__ __launch_bounds__(256) void k_sel_p3(const unsigned int* __restrict__ key, int n,
                       const int* __restrict__ state, const int2* __restrict__ bcnt,
                       int* __restrict__ nidx){
  unsigned int T = ((unsigned int)state[1] << 16) | (unsigned int)state[3];
  int m = state[4];
  int t = threadIdx.x;
  int tb = blockIdx.x*SCAN_CHUNK + t*16;
  unsigned int kk[16];
  int gt = 0, eq = 0;
#pragma unroll
  for (int j = 0; j < 16; ++j){
    int i = tb + j;
    bool ok = i < n;
    unsigned int v = ok ? key[i] : 0u;
    kk[j] = v;
    gt += (ok && v > T); eq += (ok && v == T);
  }
  __shared__ unsigned long long sh[256];
  unsigned long long mine = ((unsigned long long)(unsigned)gt << 32) | (unsigned)eq;
  sh[t] = mine; __syncthreads();
  for (int o = 1; o < 256; o <<= 1){
    unsigned long long u = (t >= o) ? sh[t-o] : 0ull;
    __syncthreads();
    sh[t] += u;
    __syncthreads();
  }
  unsigned long long excl = sh[t] - mine;
  int2 bo = bcnt[blockIdx.x];
  int gb = bo.x + (int)(excl >> 32);
  int eb = bo.y + (int)(excl & 0xffffffffu);
#pragma unroll
  for (int j = 0; j < 16; ++j){
    int i = tb + j;
    if (i >= n) break;
    unsigned int v = kk[j];
    bool g = v > T, e = v == T;
    bool sel = g || (e && eb < m);
    nidx[i] = sel ? (gb + (eb < m ? eb : m)) : -1;
    gb += g; eb += e;
  }
}

__global__ void k_pool(const float* __restrict__ X, const float* __restrict__ val,
                       const int* __restrict__ nidx, float* __restrict__ Y, int N, int C){
  int i = blockIdx.x*blockDim.x + threadIdx.x;
  int n = i / C, c = i % C;
  if (n >= N) return;
  int m = nidx[n];
  if (m >= 0) Y[(size_t)m*C + c] = X[i]*val[n];
}

__global__ void k_unpool(float* __restrict__ X, const float* __restrict__ D,
                         const int* __restrict__ nidx, int N, int C){
  int i = blockIdx.x*blockDim.x + threadIdx.x;
  int n = i / C, c = i % C;
  if (n >= N) return;
  int m = nidx[n];
  if (m >= 0) X[i] = (D[(size_t)m*C + c] + X[i])*0.5f;
}

// ---------------- launch ----------------

extern "C" void kernel_launch(void* const* d_in, const int* in_sizes, int n_in,
                              void* d_out, int out_size, void* d_ws, size_t ws_size,
                              hipStream_t stream)
{
  const float* x_in = (const float*)d_in[0];
  const int*   esrc = (const int*)d_in[1];
  const int*   edst = (const int*)d_in[2];
  const float* e0_mlp_W = (const float*)d_in[3];
  const float* e0_mlp_b = (const float*)d_in[4];
  const float* e0_bn1_g = (const float*)d_in[5];
  const float* e0_bn1_b = (const float*)d_in[6];
  const float* e0_conv_W= (const float*)d_in[7];
  const float* e0_conv_b= (const float*)d_in[8];
  const float* e0_n_g   = (const float*)d_in[9];
  const float* e0_n_b   = (const float*)d_in[10];
  const float* e1_p     = (const float*)d_in[11];
  const float* e1_mlp_W = (const float*)d_in[12];
  const float* e1_mlp_b = (const float*)d_in[13];
  const float* e1_bn1_g = (const float*)d_in[14];
  const float* e1_bn1_b = (const float*)d_in[15];
  const float* e1_conv_W= (const float*)d_in[16];
  const float* e1_conv_b= (const float*)d_in[17];
  const float* e1_n_g   = (const float*)d_in[18];
  const float* e1_n_b   = (const float*)d_in[19];
  const float* e2_p     = (const float*)d_in[20];
  const float* e2_mlp_W = (const float*)d_in[21];
  const float* e2_mlp_b = (const float*)d_in[22];
  const float* e2_bn1_g = (const float*)d_in[23];
  const float* e2_bn1_b = (const float*)d_in[24];
  const float* e2_conv_W= (const float*)d_in[25];
  const float* e2_conv_b= (const float*)d_in[26];
  const float* e2_n_g   = (const float*)d_in[27];
  const float* e2_n_b   = (const float*)d_in[28];
  const float* d2_W = (const float*)d_in[29];
  const float* d2_b = (const float*)d_in[30];
  const float* d1_W = (const float*)d_in[31];
  const float* d1_b = (const float*)d_in[32];
  const float* d0_W = (const float*)d_in[33];
  const float* d0_b = (const float*)d_in[34];
  float* out = (float*)d_out;

  const int N0 = in_sizes[0] / 16;
  const int E  = in_sizes[1];
  const int N1 = (N0 + 1) / 2;
  const int N2 = (N1 + 1) / 2;

  // ---- workspace carve ----
  char* w = (char*)d_ws;
  auto alloc = [&](size_t b)->void*{ void* p = (void*)w; w += (b + 255) & ~(size_t)255; return p; };
  float* x1 = (float*)alloc((size_t)N0*64*4);
  float* x2 = (float*)alloc((size_t)N1*128*4);
  float* x3 = (float*)alloc((size_t)N2*256*4);
  size_t tmax = (size_t)N0*64*4;
  float* tA = (float*)alloc(tmax);
  float* tB = (float*)alloc(tmax);
  int* rowptr0 = (int*)alloc((size_t)(N0+1)*4);
  int* rowptr1 = (int*)alloc((size_t)(N1+1)*4);
  int* rowptr2 = (int*)alloc((size_t)(N2+1)*4);
  int* cnt  = (int*)alloc((size_t)(N0+1)*4);
  int* fill = (int*)alloc((size_t)N0*4);
  int* cols0 = (int*)alloc((size_t)E*4);
  int* cols1 = (int*)alloc((size_t)E*4);
  int* cols2 = (int*)alloc((size_t)E*4);
  float* dinv0 = (float*)alloc((size_t)N0*4);
  float* dinv1 = (float*)alloc((size_t)N1*4);
  float* dinv2 = (float*)alloc((size_t)N2*4);
  int* nidx1 = (int*)alloc((size_t)N0*4);
  int* nidx2 = (int*)alloc((size_t)N1*4);
  float* val = (float*)alloc((size_t)N0*4);
  unsigned int* key = (unsigned int*)alloc((size_t)N0*4);
  unsigned int* hist = (unsigned int*)alloc((size_t)65536*4);
  int* state = (int*)alloc(64);
  int* bsum = (int*)alloc(1024*4);
  int2* bcnt = (int2*)alloc(1024*8);
  float* bnacc = (float*)alloc(512*4);
  float* ss = (float*)alloc(512*4);
  float* pn = (float*)alloc(256);
  if ((size_t)(w - (char*)d_ws) > ws_size) return;

  auto run_gemm = [&](const float* A, const float* W, const float* bias, float* O,
                      const float* ssA, float* stats, int N, int K, int M, int act){
    k_gemm<<<dim3(cdiv(N,64), cdiv(M,64)), dim3(256), 0, stream>>>(A, W, bias, O, ssA, stats, N, K, M, act);
  };
  auto run_scan = [&](const int* in, int* rowptr, float* dinv, int nIn){
    int nb = cdiv(nIn + 1, SCAN_CHUNK);
    k_scan_p1<<<dim3(nb), dim3(256), 0, stream>>>(in, nIn, bsum);
    k_scan_p2<<<dim3(1), dim3(256), 0, stream>>>(bsum, nb);
    k_scan_p3<<<dim3(nb), dim3(256), 0, stream>>>(in, bsum, rowptr, dinv, nIn);
  };
  auto run_agg = [&](const float* h, const int* rp, const int* cl, const float* dv,
                     const float* bias, float* o, int N, int C, int relu){
    int tpn = (C < 64) ? C : 64;
    dim3 g(cdiv(N*tpn, 256));
    switch (C){
      case 16:  k_agg<16> <<<g, dim3(256), 0, stream>>>(h, rp, cl, dv, bias, o, N, relu); break;
      case 64:  k_agg<64> <<<g, dim3(256), 0, stream>>>(h, rp, cl, dv, bias, o, N, relu); break;
      case 128: k_agg<128><<<g, dim3(256), 0, stream>>>(h, rp, cl, dv, bias, o, N, relu); break;
      case 256: k_agg<256><<<g, dim3(256), 0, stream>>>(h, rp, cl, dv, bias, o, N, relu); break;
    }
  };
  auto run_topk = [&](const float* X, const float* p, int N, int C, int k, int* nidx){
    k_pnorm<<<dim3(1), dim3(256), 0, stream>>>(p, pn, C);
    k_score<<<dim3(cdiv(N*64,256)), dim3(256), 0, stream>>>(X, p, pn, val, key, N, C);
    hipMemsetAsync(hist, 0, 65536*4, stream);
    k_hist_hi<<<dim3(cdiv(N,256)), dim3(256), 0, stream>>>(key, N, hist);
    k_scan_hist<<<dim3(1), dim3(1024), 0, stream>>>(hist, state, k, -1, 1, 2);
    hipMemsetAsync(hist, 0, 65536*4, stream);
    k_hist_lo<<<dim3(cdiv(N,256)), dim3(256), 0, stream>>>(key, N, state, hist);
    k_scan_hist<<<dim3(1), dim3(1024), 0, stream>>>(hist, state, 0, 2, 3, 4);
    int nb = cdiv(N, SCAN_CHUNK);
    k_sel_p1<<<dim3(nb), dim3(256), 0, stream>>>(key, N, state, bcnt);
    k_sel_p2<<<dim3(1), dim3(256), 0, stream>>>(bcnt, nb);
    k_sel_p3<<<dim3(nb), dim3(256), 0, stream>>>(key, N, state, bcnt, nidx);
  };

  // ---- CSR level 0 ----
  hipMemsetAsync(cnt, 0, (size_t)(N0+1)*4, stream);
  k_count0<<<dim3(cdiv(E,256)), dim3(256), 0, stream>>>(edst, cnt, E);
  run_scan(cnt, rowptr0, dinv0, N0);
  hipMemsetAsync(fill, 0, (size_t)N0*4, stream);
  k_fill0<<<dim3(cdiv(E,256)), dim3(256), 0, stream>>>(esrc, edst, rowptr0, fill, cols0, E);

  // ---- encoder0 ----
  hipMemsetAsync(bnacc, 0, 2*64*4, stream);
  run_gemm(x_in, e0_mlp_W, e0_mlp_b, tA, nullptr, bnacc, N0, 16, 64, 1);
  k_bn_final<<<dim3(1), dim3(64), 0, stream>>>(bnacc, e0_bn1_g, e0_bn1_b, ss, N0, 64);
  run_gemm(tA, e0_conv_W, nullptr, tB, ss, nullptr, N0, 64, 64, 0);
  run_agg(tB, rowptr0, cols0, dinv0, e0_conv_b, tA, N0, 64, 0);
  hipMemsetAsync(bnacc, 0, 2*64*4, stream);
  k_bn_stats<<<dim3(256), dim3(256), 0, stream>>>(tA, bnacc, N0, 64);
  k_bn_final<<<dim3(1), dim3(64), 0, stream>>>(bnacc, e0_n_g, e0_n_b, ss, N0, 64);
  k_bn_apply<<<dim3(cdiv(N0*64,256)), dim3(256), 0, stream>>>(tA, x1, ss, N0*64, 64, 1);

  // ---- pool1 + CSR level 1 ----
  run_topk(x1, e1_p, N0, 64, N1, nidx1);
  k_pool<<<dim3(cdiv(N0*64,256)), dim3(256), 0, stream>>>(x1, val, nidx1, tA, N0, 64);
  hipMemsetAsync(cnt, 0, (size_t)(N1+1)*4, stream);
  k_count_mapped<<<dim3(cdiv(E,256)), dim3(256), 0, stream>>>(esrc, edst, nidx1, cnt, E);
  run_scan(cnt, rowptr1, dinv1, N1);
  hipMemsetAsync(fill, 0, (size_t)N1*4, stream);
  k_fill_mapped<<<dim3(cdiv(E,256)), dim3(256), 0, stream>>>(esrc, edst, nidx1, rowptr1, fill, cols1, E);

  // ---- encoder1 ----
  hipMemsetAsync(bnacc, 0, 2*128*4, stream);
  run_gemm(tA, e1_mlp_W, e1_mlp_b, tB, nullptr, bnacc, N1, 64, 128, 1);
  k_bn_final<<<dim3(1), dim3(128), 0, stream>>>(bnacc, e1_bn1_g, e1_bn1_b, ss, N1, 128);
  run_gemm(tB, e1_conv_W, nullptr, tA, ss, nullptr, N1, 128, 128, 0);
  run_agg(tA, rowptr1, cols1, dinv1, e1_conv_b, tB, N1, 128, 0);
  hipMemsetAsync(bnacc, 0, 2*128*4, stream);
  k_bn_stats<<<dim3(256), dim3(256), 0, stream>>>(tB, bnacc, N1, 128);
  k_bn_final<<<dim3(1), dim3(128), 0, stream>>>(bnacc, e1_n_g, e1_n_b, ss, N1, 128);
  k_bn_apply<<<dim3(cdiv(N1*128,256)), dim3(256), 0, stream>>>(tB, x2, ss, N1*128, 128, 1);

  // ---- pool2 + CSR level 2 ----
  run_topk(x2, e2_p, N1, 128, N2, nidx2);
  k_pool<<<dim3(cdiv(N1*128,256)), dim3(256), 0, stream>>>(x2, val, nidx2, tA, N1, 128);
  k_count_csr<<<dim3(cdiv(N1,256)), dim3(256), 0, stream>>>(rowptr1, cols1, nidx2, cnt, N1);
  run_scan(cnt, rowptr2, dinv2, N2);
  k_fill_csr<<<dim3(cdiv(N1,256)), dim3(256), 0, stream>>>(rowptr1, cols1, nidx2, rowptr2, cols2, N1);

  // ---- encoder2 ----
  hipMemsetAsync(bnacc, 0, 2*256*4, stream);
  run_gemm(tA, e2_mlp_W, e2_mlp_b, tB, nullptr, bnacc, N2, 128, 256, 1);
  k_bn_final<<<dim3(1), dim3(256), 0, stream>>>(bnacc, e2_bn1_g, e2_bn1_b, ss, N2, 256);
  run_gemm(tB, e2_conv_W, nullptr, tA, ss, nullptr, N2, 256, 256, 0);
  run_agg(tA, rowptr2, cols2, dinv2, e2_conv_b, tB, N2, 256, 0);
  hipMemsetAsync(bnacc, 0, 2*256*4, stream);
  k_bn_stats<<<dim3(256), dim3(256), 0, stream>>>(tB, bnacc, N2, 256);
  k_bn_final<<<dim3(1), dim3(256), 0, stream>>>(bnacc, e2_n_g, e2_n_b, ss, N2, 256);
  k_bn_apply<<<dim3(cdiv(N2*256,256)), dim3(256), 0, stream>>>(tB, x3, ss, N2*256, 256, 1);

  // ---- decoder2 + unpool into x2 ----
  run_gemm(x3, d2_W, nullptr, tA, nullptr, nullptr, N2, 256, 128, 0);
  run_agg(tA, rowptr2, cols2, dinv2, d2_b, tB, N2, 128, 1);
  k_unpool<<<dim3(cdiv(N1*128,256)), dim3(256), 0, stream>>>(x2, tB, nidx2, N1, 128);

  // ---- decoder1 + unpool into x1 ----
  run_gemm(x2, d1_W, nullptr, tA, nullptr, nullptr, N1, 128, 64, 0);
  run_agg(tA, rowptr1, cols1, dinv1, d1_b, tB, N1, 64, 1);
  k_unpool<<<dim3(cdiv(N0*64,256)), dim3(256), 0, stream>>>(x1, tB, nidx1, N0, 64);

  // ---- decoder0 -> output ----
  run_gemm(x1, d0_W, nullptr, tA, nullptr, nullptr, N0, 64, 16, 0);
  run_agg(tA, rowptr0, cols0, dinv0, d0_b, out, N0, 16, 0);
}